// Round 7
// baseline (5650.193 us; speedup 1.0000x reference)
//
#include <hip/hip_runtime.h>
#include <cmath>

typedef float  f32x4  __attribute__((ext_vector_type(4)));
typedef float  f32x2  __attribute__((ext_vector_type(2)));
typedef __bf16 bf16x8 __attribute__((ext_vector_type(8)));

static constexpr int HN  = 1024;     // hidden
static constexpr int VN  = 32000;    // vocab
static constexpr int BN  = 8;        // batch
static constexpr int SN  = 256;      // seq
static constexpr int H4N = 4096;     // 4*H

// ---------------------------------------------------------------------------
// xp0[t][b][r] = w_ih0[r][x[b][t]] + b_ih0[r] + b_hh0[r]
// ---------------------------------------------------------------------------
__global__ __launch_bounds__(256) void k_gather(const int* __restrict__ x,
    const float* __restrict__ w_ih0, const float* __restrict__ b_ih0,
    const float* __restrict__ b_hh0, float* __restrict__ xp) {
  int bid = blockIdx.x;
  int t = bid >> 3, b = bid & 7;
  int tok = x[b * SN + t];
  const float* col = w_ih0 + tok;           // column tok, stride VN
  float* dst = xp + (size_t)bid * H4N;
  for (int r = threadIdx.x; r < H4N; r += 256)
    dst[r] = col[(size_t)r * VN] + b_ih0[r] + b_hh0[r];
}

// ---------------------------------------------------------------------------
// Persistent LSTM layer. grid MUST be 256 blocks x 256 thr, 1 block/CU
// (113KB LDS enforces it -> exactly 32 blocks per XCD).
//
// XCD-hierarchical exchange (cross-XCD safe, replay-safe):
//   write h  : relaxed agent atomic stores (write-through -> MALL)
//   arrive   : wave-0 s_waitcnt vmcnt(0), relaxed agent fetch_add,
//              64 counters x 4 blocks (R5-proven fan-in)
//   leaders  : 1 per PHYSICAL XCD (s_getreg XCC_ID + election). Only the 8
//              leaders poll global counters; leader pulls full h (32KB) from
//              MALL once, writes it into per-XCD xbuf with plain write-back
//              stores (lands in own XCD L2), bumps per-XCD flag (MALL RMW).
//   followers: poll flag (MALL load, 1 lane), then read xbuf with sc0
//              L1-bypass loads -> served from local L2 (32x less MALL read
//              traffic than R5). xbuf parity-double-buffered; WAR safe via
//              the global barrier (leader can't lead any follower by 2).
// ---------------------------------------------------------------------------
__global__ __launch_bounds__(256, 1) void k_lstm(
    const float* __restrict__ xp,    // [S][B][4H]
    const float* __restrict__ w_hh,  // [4H][H]
    const float* __restrict__ h0,    // [B][H] (this layer)
    const float* __restrict__ c0,    // [B][H]
    float* __restrict__ hs,          // [S][B][H] out (also h exchange buffer)
    float* __restrict__ hn, float* __restrict__ cn,   // [B][H]
    unsigned* __restrict__ bar,      // 64 counters, stride 32 uints
    unsigned* __restrict__ flag,     // 8 flags, stride 32 uints
    unsigned* __restrict__ elect,    // 8 counters, stride 32 uints
    float* __restrict__ xbuf) {      // [2 parity][8 xcd][8192]
  __shared__ float wL[16][1024];          // 64KB, row = g*4+u, swizzled
  __shared__ float hL[8192];              // 32KB, chunk idx (k4*8+b)^((k4>>3)&7)
  __shared__ float red[8][4][4][32];      // 16KB [rg*2+bg][ri][bi][ks]
  __shared__ float gates[16][8];
  __shared__ float cL[32];                // [u*8+b]
  __shared__ unsigned meta[2];            // [0]=phys xcd, [1]=election idx

  const int tid = threadIdx.x;
  const int wg  = blockIdx.x;
  const int u0  = wg * 4;

  // ---- physical-XCD identification + leader election (once)
  unsigned xcc;
  asm volatile("s_getreg_b32 %0, hwreg(HW_REG_XCC_ID)" : "=s"(xcc));
  if (tid == 0) {
    meta[0] = xcc & 7;
    meta[1] = __hip_atomic_fetch_add(&elect[(xcc & 7) * 32], 1u,
                                     __ATOMIC_RELAXED, __HIP_MEMORY_SCOPE_AGENT);
  }

  // ---- load weight slice into LDS once
  for (int it = 0; it < 16; ++it) {
    int g = it >> 2, u = it & 3;
    int k4 = tid;
    int k4s = k4 ^ ((k4 >> 3) & 7);       // swizzle within row
    f32x4 v = *(const f32x4*)&w_hh[((size_t)g * HN + u0 + u) * HN + k4 * 4];
    *(f32x4*)&wL[it][k4s * 4] = v;
  }
  if (tid < 32) cL[tid] = c0[(tid & 7) * HN + u0 + (tid >> 3)];
  __syncthreads();
  const int  myxcd  = (int)meta[0];
  const bool leader = (meta[1] == 0u);

  const int ks = tid & 31, rg = (tid >> 5) & 3, bg = tid >> 7;
  const int ksx = ks & 7;
  const int hb = tid & 7;                  // batch row this thread stages
  const int hk = tid >> 3;                 // u64 lane within row, 0..31

  // xp-prefetch indexing (tid<128: one (gate-row, batch) each)
  const int prow = tid >> 3, pb = tid & 7;
  const int pg = prow >> 2, pu = prow & 3;
  const size_t pofs = (size_t)pb * H4N + (size_t)pg * HN + u0 + pu;

  for (int t = 0; t < SN; ++t) {
    // ---- prefetch xp for THIS step (independent of h; hides LLC latency)
    float xpv = 0.f;
    if (tid < 128) xpv = xp[(size_t)t * (BN * H4N) + pofs];

    // ---- obtain h(t-1) into rv[16] (u64 view of this thread's slice)
    float* xbp = xbuf + ((size_t)(t & 1) * 8 + myxcd) * 8192;
    unsigned long long rv[16];
    if (t == 0) {
      const unsigned long long* s8 =
          (const unsigned long long*)h0 + (size_t)hb * 512 + hk;
      #pragma unroll
      for (int j = 0; j < 16; ++j) rv[j] = s8[j * 32];
    } else if (leader) {
      // wait for ALL 256 blocks' step-(t-1) h stores (64 lanes x 64 ctrs)
      if (tid < 64) {
        unsigned tgt = 4u * (unsigned)t;
        while (__hip_atomic_load(&bar[tid * 32], __ATOMIC_RELAXED,
                                 __HIP_MEMORY_SCOPE_AGENT) < tgt)
          __builtin_amdgcn_s_sleep(1);
      }
      __syncthreads();
      // pull full h from MALL (only 8 blocks grid-wide do this)
      const unsigned long long* hsrc8 =
          (const unsigned long long*)(hs + (size_t)(t - 1) * (BN * HN))
          + (size_t)hb * 512 + hk;
      #pragma unroll
      for (int j = 0; j < 16; ++j)
        rv[j] = __hip_atomic_load((unsigned long long*)(hsrc8 + j * 32),
                                  __ATOMIC_RELAXED, __HIP_MEMORY_SCOPE_AGENT);
      // publish into own XCD's L2 (plain write-back stores)
      unsigned long long* xb8 =
          (unsigned long long*)xbp + (size_t)hb * 512 + hk;
      #pragma unroll
      for (int j = 0; j < 16; ++j) xb8[j * 32] = rv[j];
    } else {
      // wait for my XCD's leader flag (MALL load, 1 lane)
      if (tid == 0) {
        while (__hip_atomic_load(&flag[myxcd * 32], __ATOMIC_RELAXED,
                                 __HIP_MEMORY_SCOPE_AGENT) < (unsigned)t)
          __builtin_amdgcn_s_sleep(1);
      }
      __syncthreads();
      // read leader's copy from local L2 with L1-bypass (sc0) loads
      const unsigned long long* xb8 =
          (const unsigned long long*)xbp + (size_t)hb * 512 + hk;
      unsigned long long a = (unsigned long long)xb8;
      unsigned long long r0, r1, r2, r3, r4, r5, r6, r7;
      unsigned long long r8, r9, r10, r11, r12, r13, r14, r15;
      asm volatile(
        "global_load_dwordx2 %0, %16, off sc0\n\t"
        "global_load_dwordx2 %1, %16, off offset:256 sc0\n\t"
        "global_load_dwordx2 %2, %16, off offset:512 sc0\n\t"
        "global_load_dwordx2 %3, %16, off offset:768 sc0\n\t"
        "global_load_dwordx2 %4, %16, off offset:1024 sc0\n\t"
        "global_load_dwordx2 %5, %16, off offset:1280 sc0\n\t"
        "global_load_dwordx2 %6, %16, off offset:1536 sc0\n\t"
        "global_load_dwordx2 %7, %16, off offset:1792 sc0\n\t"
        "global_load_dwordx2 %8, %16, off offset:2048 sc0\n\t"
        "global_load_dwordx2 %9, %16, off offset:2304 sc0\n\t"
        "global_load_dwordx2 %10, %16, off offset:2560 sc0\n\t"
        "global_load_dwordx2 %11, %16, off offset:2816 sc0\n\t"
        "global_load_dwordx2 %12, %16, off offset:3072 sc0\n\t"
        "global_load_dwordx2 %13, %16, off offset:3328 sc0\n\t"
        "global_load_dwordx2 %14, %16, off offset:3584 sc0\n\t"
        "global_load_dwordx2 %15, %16, off offset:3840 sc0\n\t"
        "s_waitcnt vmcnt(0)"
        : "=&v"(r0), "=&v"(r1), "=&v"(r2), "=&v"(r3),
          "=&v"(r4), "=&v"(r5), "=&v"(r6), "=&v"(r7),
          "=&v"(r8), "=&v"(r9), "=&v"(r10), "=&v"(r11),
          "=&v"(r12), "=&v"(r13), "=&v"(r14), "=&v"(r15)
        : "v"(a) : "memory");
      rv[0] = r0;  rv[1] = r1;  rv[2] = r2;  rv[3] = r3;
      rv[4] = r4;  rv[5] = r5;  rv[6] = r6;  rv[7] = r7;
      rv[8] = r8;  rv[9] = r9;  rv[10] = r10; rv[11] = r11;
      rv[12] = r12; rv[13] = r13; rv[14] = r14; rv[15] = r15;
    }

    // ---- common: swizzle-store rv -> hL
    #pragma unroll
    for (int j = 0; j < 16; ++j) {
      int k64 = hk + j * 32;               // u64 index within the row
      int k4 = k64 >> 1, half = k64 & 1;
      int idx = ((k4 << 3) | hb) ^ ((k4 >> 3) & 7);
      *(f32x2*)&hL[idx * 4 + half * 2] = __builtin_bit_cast(f32x2, rv[j]);
    }
    __syncthreads();   // hL ready; also drains leader's xbuf stores (vmcnt 0)
    if (t > 0 && leader && tid == 0)
      __hip_atomic_fetch_add(&flag[myxcd * 32], 1u,
                             __ATOMIC_RELAXED, __HIP_MEMORY_SCOPE_AGENT);

    // ---- gate matmul partials: 512 FMA, 64 ds_read_b128 per thread
    float acc[4][4] = {};
    #pragma unroll
    for (int j = 0; j < 8; ++j) {
      int k4 = ks * 8 + j;
      int k4s = k4 ^ ksx;
      f32x4 wv[4], hv[4];
      #pragma unroll
      for (int ri = 0; ri < 4; ++ri)
        wv[ri] = *(const f32x4*)&wL[rg * 4 + ri][k4s * 4];
      #pragma unroll
      for (int bi = 0; bi < 4; ++bi) {
        int idx = ((k4 << 3) | (bg * 4 + bi)) ^ ksx;
        hv[bi] = *(const f32x4*)&hL[idx * 4];
      }
      #pragma unroll
      for (int ri = 0; ri < 4; ++ri)
        #pragma unroll
        for (int bi = 0; bi < 4; ++bi)
          acc[ri][bi] += wv[ri][0]*hv[bi][0] + wv[ri][1]*hv[bi][1]
                       + wv[ri][2]*hv[bi][2] + wv[ri][3]*hv[bi][3];
    }
    #pragma unroll
    for (int ri = 0; ri < 4; ++ri)
      #pragma unroll
      for (int bi = 0; bi < 4; ++bi)
        red[rg * 2 + bg][ri][bi][ks] = acc[ri][bi];
    __syncthreads();

    // ---- reduce over ks (128 threads: one per (gate-row, batch))
    if (tid < 128) {
      int rrg = prow >> 2, ri = prow & 3, bbg = pb >> 2, bi = pb & 3;
      const float* rp = red[rrg * 2 + bbg][ri][bi];
      float s = 0.f;
      #pragma unroll
      for (int q = 0; q < 32; ++q) s += rp[(q + tid) & 31];  // bank-rotated
      gates[prow][pb] = s + xpv;
    }
    __syncthreads();

    // ---- nonlinearity + state update (32 threads: (u,b), all in wave 0)
    if (tid < 32) {
      int u = tid >> 3, b = tid & 7;
      float gi = gates[0 * 4 + u][b], gf = gates[1 * 4 + u][b];
      float gg = gates[2 * 4 + u][b], go = gates[3 * 4 + u][b];
      float si = 1.f / (1.f + expf(-gi));
      float sf = 1.f / (1.f + expf(-gf));
      float so = 1.f / (1.f + expf(-go));
      float c = sf * cL[tid] + si * tanhf(gg);
      float h = so * tanhf(c);
      cL[tid] = c;
      // write-through to coherence point (MALL)
      __hip_atomic_store(&hs[(size_t)t * (BN * HN) + b * HN + u0 + u], h,
                         __ATOMIC_RELAXED, __HIP_MEMORY_SCOPE_AGENT);
      if (t == SN - 1) {
        hn[b * HN + u0 + u] = h;
        cn[b * HN + u0 + u] = c;
      }
    }

    if (t != SN - 1) {
      // arrive: tid0 shares wave 0 with the 32 h-store lanes, so vmcnt(0)
      // orders those stores at the MALL before the counter add
      if (tid == 0) {
        asm volatile("s_waitcnt vmcnt(0)" ::: "memory");
        __hip_atomic_fetch_add(&bar[(wg >> 2) * 32], 1u,
                               __ATOMIC_RELAXED, __HIP_MEMORY_SCOPE_AGENT);
      }
      __syncthreads();
    } else {
      __syncthreads();
    }
  }
}

// ---------------------------------------------------------------------------
// fp32 -> (bf16 hi, bf16 lo) split
// ---------------------------------------------------------------------------
__global__ __launch_bounds__(256) void k_split(const float* __restrict__ src,
    __bf16* __restrict__ hi, __bf16* __restrict__ lo) {
  int i = (blockIdx.x * 256 + threadIdx.x) * 4;
  f32x4 v = *(const f32x4*)&src[i];
  #pragma unroll
  for (int j = 0; j < 4; ++j) {
    __bf16 h = (__bf16)v[j];
    hi[i + j] = h;
    lo[i + j] = (__bf16)(v[j] - (float)h);
  }
}

// ---------------------------------------------------------------------------
// C[M=2048][N] = A[2048][1024] * Bsrc[N][1024]^T + bias1(+bias2), via
// 3-term bf16 split MFMA. 128x128 tile, BK=32, 4 waves.
// permute=1: output row m=t*8+b is written to row b*256+t (logits layout).
// ---------------------------------------------------------------------------
__global__ __launch_bounds__(256) void k_gemm(const __bf16* __restrict__ Ahi,
    const __bf16* __restrict__ Alo, const float* __restrict__ Bsrc,
    const float* __restrict__ bias1, const float* __restrict__ bias2,
    float* __restrict__ C, int Mt, int N, int permute) {
  __shared__ __bf16 sAh[128][32], sAl[128][32], sBh[128][32], sBl[128][32];
  int bid = blockIdx.x;
  int tn = bid / Mt, tm = bid % Mt;           // m-fastest: B-strip L2 reuse
  int tid = threadIdx.x, lane = tid & 63, wid = tid >> 6;
  int wr = wid >> 1, wc = wid & 1;
  f32x4 acc[4][4] = {};
  const size_t K = 1024;

  for (int kk = 0; kk < 1024; kk += 32) {
    __syncthreads();
    #pragma unroll
    for (int it = 0; it < 2; ++it) {
      int c = it * 256 + tid;                  // 512 chunks of bf16x8
      int r = c >> 2, k8 = (c & 3) * 8;
      size_t ga = (size_t)(tm * 128 + r) * K + kk + k8;
      *(bf16x8*)&sAh[r][k8] = *(const bf16x8*)&Ahi[ga];
      *(bf16x8*)&sAl[r][k8] = *(const bf16x8*)&Alo[ga];
      size_t gb = (size_t)(tn * 128 + r) * K + kk + k8;
      f32x4 x0 = *(const f32x4*)&Bsrc[gb];
      f32x4 x1 = *(const f32x4*)&Bsrc[gb + 4];
      bf16x8 bh, bl;
      #pragma unroll
      for (int j = 0; j < 4; ++j) {
        __bf16 h0 = (__bf16)x0[j]; bh[j]     = h0; bl[j]     = (__bf16)(x0[j] - (float)h0);
        __bf16 h1 = (__bf16)x1[j]; bh[4 + j] = h1; bl[4 + j] = (__bf16)(x1[j] - (float)h1);
      }
      *(bf16x8*)&sBh[r][k8] = bh;
      *(bf16x8*)&sBl[r][k8] = bl;
    }
    __syncthreads();

    int kq = (lane >> 4) * 8;
    bf16x8 ah[4], al[4], bh[4], bl[4];
    #pragma unroll
    for (int i = 0; i < 4; ++i) {
      int ra = wr * 64 + i * 16 + (lane & 15);
      ah[i] = *(const bf16x8*)&sAh[ra][kq];
      al[i] = *(const bf16x8*)&sAl[ra][kq];
      int rb = wc * 64 + i * 16 + (lane & 15);
      bh[i] = *(const bf16x8*)&sBh[rb][kq];
      bl[i] = *(const bf16x8*)&sBl[rb][kq];
    }
    #pragma unroll
    for (int i = 0; i < 4; ++i)
      #pragma unroll
      for (int j = 0; j < 4; ++j) {
        acc[i][j] = __builtin_amdgcn_mfma_f32_16x16x32_bf16(ah[i], bh[j], acc[i][j], 0, 0, 0);
        acc[i][j] = __builtin_amdgcn_mfma_f32_16x16x32_bf16(ah[i], bl[j], acc[i][j], 0, 0, 0);
        acc[i][j] = __builtin_amdgcn_mfma_f32_16x16x32_bf16(al[i], bh[j], acc[i][j], 0, 0, 0);
      }
  }

  // epilogue: C/D layout col=lane&15, row=(lane>>4)*4+reg (m89-verified)
  #pragma unroll
  for (int j = 0; j < 4; ++j) {
    int gcol = tn * 128 + wc * 64 + j * 16 + (lane & 15);
    float bv = bias1[gcol] + (bias2 ? bias2[gcol] : 0.f);
    #pragma unroll
    for (int i = 0; i < 4; ++i) {
      #pragma unroll
      for (int r = 0; r < 4; ++r) {
        int row = tm * 128 + wr * 64 + i * 16 + ((lane >> 4) << 2) + r;
        int orow = permute ? ((row & 7) * 256 + (row >> 3)) : row;
        C[(size_t)orow * N + gcol] = acc[i][j][r] + bv;
      }
    }
  }
}

// ---------------------------------------------------------------------------
extern "C" void kernel_launch(void* const* d_in, const int* in_sizes, int n_in,
                              void* d_out, int out_size, void* d_ws, size_t ws_size,
                              hipStream_t stream) {
  (void)in_sizes; (void)n_in; (void)out_size; (void)ws_size;
  const int*   x     = (const int*)  d_in[0];
  const float* h0    = (const float*)d_in[1];
  const float* c0    = (const float*)d_in[2];
  const float* w_ih0 = (const float*)d_in[3];
  const float* w_hh0 = (const float*)d_in[4];
  const float* b_ih0 = (const float*)d_in[5];
  const float* b_hh0 = (const float*)d_in[6];
  const float* w_ih1 = (const float*)d_in[7];
  const float* w_hh1 = (const float*)d_in[8];
  const float* b_ih1 = (const float*)d_in[9];
  const float* b_hh1 = (const float*)d_in[10];
  const float* fc_w  = (const float*)d_in[11];
  const float* fc_b  = (const float*)d_in[12];
  float* out = (float*)d_out;
  float* ws  = (float*)d_ws;

  // ws layout (floats)
  float* xp   = ws;                        // [S][B][4H] = 8,388,608
  float* h1s  = ws + 8388608;              // [S][B][H]  = 2,097,152
  float* h2s  = ws + 10485760;             // 2,097,152
  __bf16* Ahi = (__bf16*)(ws + 12582912);  // 2048*1024 bf16 = 1,048,576 floats
  __bf16* Alo = (__bf16*)(ws + 13631488);  // 1,048,576 floats
  unsigned* U = (unsigned*)(ws + 14680064);
  // bar: [0,4096) (2 layers x 64 x 32); flag: [4096,4608); elect: [4608,5120)
  unsigned* bar0   = U;
  unsigned* bar1   = U + 2048;
  unsigned* flag0  = U + 4096;
  unsigned* flag1  = U + 4352;
  unsigned* elect0 = U + 4608;
  unsigned* elect1 = U + 4864;
  float* xbuf0 = ws + 14688256;            // 2 x 8 x 8192 = 131072 floats
  float* xbuf1 = ws + 14819328;            // 131072 floats

  const size_t LOG = (size_t)2048 * VN;    // 65,536,000
  float* hn = out + LOG;                   // [2][8][1024]
  float* cn = out + LOG + 16384;           // [2][8][1024]

  hipMemsetAsync(U, 0, 5120 * sizeof(unsigned), stream);

  k_gather<<<SN * BN, 256, 0, stream>>>(x, w_ih0, b_ih0, b_hh0, xp);

  // ---- layer 0 (persistent, 256 blocks = 256 CUs) ----
  k_lstm<<<256, 256, 0, stream>>>(xp, w_hh0, h0, c0, h1s, hn, cn,
                                  bar0, flag0, elect0, xbuf0);

  k_split<<<2048, 256, 0, stream>>>(h1s, Ahi, Alo);
  // xp1 = h1s @ w_ih1^T + (b_ih1 + b_hh1)   (M=2048, N=4096)
  k_gemm<<<16 * 32, 256, 0, stream>>>(Ahi, Alo, w_ih1, b_ih1, b_hh1, xp,
                                      16, H4N, 0);

  // ---- layer 1 ----
  k_lstm<<<256, 256, 0, stream>>>(xp, w_hh1, h0 + BN * HN, c0 + BN * HN,
                                  h2s, hn + BN * HN, cn + BN * HN,
                                  bar1, flag1, elect1, xbuf1);

  k_split<<<2048, 256, 0, stream>>>(h2s, Ahi, Alo);
  // logits = h2s @ fc_w^T + fc_b  (M=2048, N=32000), row-permuted to b*S+t
  k_gemm<<<16 * 250, 256, 0, stream>>>(Ahi, Alo, fc_w, fc_b, nullptr, out,
                                       16, VN, 1);
}

// Round 8
// 5104.977 us; speedup vs baseline: 1.1068x; 1.1068x over previous
//
#include <hip/hip_runtime.h>
#include <cmath>

typedef float  f32x4  __attribute__((ext_vector_type(4)));
typedef float  f32x2  __attribute__((ext_vector_type(2)));
typedef __bf16 bf16x8 __attribute__((ext_vector_type(8)));

static constexpr int HN  = 1024;     // hidden
static constexpr int VN  = 32000;    // vocab
static constexpr int BN  = 8;        // batch
static constexpr int SN  = 256;      // seq
static constexpr int H4N = 4096;     // 4*H

// ---------------------------------------------------------------------------
// Persistent LSTM layer, pure-dataflow sync. grid MUST be 256 x 256, 1
// block/CU (124KB LDS enforces it). Block wg owns units [wg*4, wg*4+4).
//
// Per-step protocol (no barrier, no counters, 2 MALL round-trips):
//   producer: store 32 h values (relaxed agent, write-through -> MALL),
//             same-wave s_waitcnt vmcnt(0), store tag[t][wg] = t+1.
//   consumer: thread tid polls tag[t-1][tid] (relaxed agent) until == t,
//             __syncthreads (all 256 producers confirmed), then sc1 u64
//             h loads. Data is at MALL before its tag (producer vmcnt).
//   hs slots are write-once per call -> no WAR hazard, drift bound = 1 step.
//   tags zeroed via hipMemsetAsync before each layer (replay-safe).
//
// Layer 0 fuses the one-hot gather: xpv = w_ih0[row*VN + tok[t][b]] + bias
// (tokens staged in LDS once; bias preloaded; load issued at loop top so
// its ~900ns HBM latency hides under the tag poll).
// ---------------------------------------------------------------------------
__global__ __launch_bounds__(256, 1) void k_lstm(
    const float* __restrict__ xp,    // [S][B][4H] (layer1) or ignored (layer0)
    const float* __restrict__ wtok,  // layer0: w_ih0 [4H][V]; layer1: null
    const int*   __restrict__ xtok,  // layer0: x [B][S]; layer1: null
    const float* __restrict__ bi,    // layer0: b_ih0; layer1: null
    const float* __restrict__ bh,    // layer0: b_hh0; layer1: null
    const float* __restrict__ w_hh,  // [4H][H]
    const float* __restrict__ h0,    // [B][H] (this layer)
    const float* __restrict__ c0,    // [B][H]
    float* __restrict__ hs,          // [S][B][H] out (also h exchange buffer)
    float* __restrict__ hn, float* __restrict__ cn,   // [B][H]
    unsigned* __restrict__ tags) {   // [S][256]
  __shared__ float wL[16][1024];          // 64KB, row = g*4+u, swizzled
  __shared__ float hL[8192];              // 32KB, chunk idx (k4*8+b)^((k4>>3)&7)
  __shared__ float red[8][4][4][32];      // 16KB [rg*2+bg][ri][bi][ks]
  __shared__ float gates[16][8];
  __shared__ float cL[32];                // [u*8+b]
  __shared__ int   tokL[SN * BN / 2 * 0 + 2048];  // 8KB [t*8+b] (layer0)

  const int tid = threadIdx.x;
  const int wg  = blockIdx.x;
  const int u0  = wg * 4;

  // ---- load weight slice into LDS once
  for (int it = 0; it < 16; ++it) {
    int g = it >> 2, u = it & 3;
    int k4 = tid;
    int k4s = k4 ^ ((k4 >> 3) & 7);       // swizzle within row
    f32x4 v = *(const f32x4*)&w_hh[((size_t)g * HN + u0 + u) * HN + k4 * 4];
    *(f32x4*)&wL[it][k4s * 4] = v;
  }
  if (tid < 32) cL[tid] = c0[(tid & 7) * HN + u0 + (tid >> 3)];
  // ---- stage tokens (layer 0 only): tokL[t*8+b] = x[b][t]
  if (xtok) {
    for (int j = 0; j < 8; ++j) {
      int idx = j * 256 + tid;             // b = idx>>8, t = idx&255
      tokL[(idx & 255) * 8 + (idx >> 8)] = xtok[idx];
    }
  }

  const int ks = tid & 31, rg = (tid >> 5) & 3, bg = tid >> 7;
  const int ksx = ks & 7;
  const int hb = tid & 7;                  // batch row this thread stages
  const int hk = tid >> 3;                 // u64 lane within row, 0..31

  // xp/gather indexing (tid<128: one (gate-row, batch) each)
  const int prow = tid >> 3, pb = tid & 7;
  const int pg = prow >> 2, pu = prow & 3;
  const int growg = pg * HN + u0 + pu;     // global gate row
  const size_t pofs = (size_t)pb * H4N + growg;
  float bsum = 0.f;
  if (bi && tid < 128) bsum = bi[growg] + bh[growg];
  __syncthreads();                         // wL/tokL ready

  for (int t = 0; t < SN; ++t) {
    // ---- issue xp/gather load for THIS step first (hides under poll)
    float xpv = 0.f;
    if (tid < 128) {
      if (wtok) {
        int tok = tokL[t * 8 + pb];
        xpv = wtok[(size_t)growg * VN + tok] + bsum;
      } else {
        xpv = xp[(size_t)t * (BN * H4N) + pofs];
      }
    }

    // ---- wait for step t-1 producers (1 tag per thread), then load h
    unsigned long long rv[16];
    if (t == 0) {
      const unsigned long long* s8 =
          (const unsigned long long*)h0 + (size_t)hb * 512 + hk;
      #pragma unroll
      for (int j = 0; j < 16; ++j) rv[j] = s8[j * 32];
    } else {
      const unsigned* tg = tags + (size_t)(t - 1) * 256 + tid;
      while (__hip_atomic_load(tg, __ATOMIC_RELAXED,
                               __HIP_MEMORY_SCOPE_AGENT) != (unsigned)t)
        __builtin_amdgcn_s_sleep(1);
      __syncthreads();                     // all 256 producers confirmed
      const unsigned long long* hsrc8 =
          (const unsigned long long*)(hs + (size_t)(t - 1) * (BN * HN))
          + (size_t)hb * 512 + hk;
      #pragma unroll
      for (int j = 0; j < 16; ++j)
        rv[j] = __hip_atomic_load((unsigned long long*)(hsrc8 + j * 32),
                                  __ATOMIC_RELAXED, __HIP_MEMORY_SCOPE_AGENT);
    }

    // ---- swizzle-store rv -> hL
    #pragma unroll
    for (int j = 0; j < 16; ++j) {
      int k64 = hk + j * 32;               // u64 index within the row
      int k4 = k64 >> 1, half = k64 & 1;
      int idx = ((k4 << 3) | hb) ^ ((k4 >> 3) & 7);
      *(f32x2*)&hL[idx * 4 + half * 2] = __builtin_bit_cast(f32x2, rv[j]);
    }
    __syncthreads();

    // ---- gate matmul partials: 512 FMA, 64 ds_read_b128 per thread
    float acc[4][4] = {};
    #pragma unroll
    for (int j = 0; j < 8; ++j) {
      int k4 = ks * 8 + j;
      int k4s = k4 ^ ksx;
      f32x4 wv[4], hv[4];
      #pragma unroll
      for (int ri = 0; ri < 4; ++ri)
        wv[ri] = *(const f32x4*)&wL[rg * 4 + ri][k4s * 4];
      #pragma unroll
      for (int bi2 = 0; bi2 < 4; ++bi2) {
        int idx = ((k4 << 3) | (bg * 4 + bi2)) ^ ksx;
        hv[bi2] = *(const f32x4*)&hL[idx * 4];
      }
      #pragma unroll
      for (int ri = 0; ri < 4; ++ri)
        #pragma unroll
        for (int bi2 = 0; bi2 < 4; ++bi2)
          acc[ri][bi2] += wv[ri][0]*hv[bi2][0] + wv[ri][1]*hv[bi2][1]
                        + wv[ri][2]*hv[bi2][2] + wv[ri][3]*hv[bi2][3];
    }
    #pragma unroll
    for (int ri = 0; ri < 4; ++ri)
      #pragma unroll
      for (int bi2 = 0; bi2 < 4; ++bi2)
        red[rg * 2 + bg][ri][bi2][ks] = acc[ri][bi2];
    __syncthreads();

    // ---- reduce over ks (128 threads: one per (gate-row, batch))
    if (tid < 128) {
      int rrg = prow >> 2, ri = prow & 3, bbg = pb >> 2, bi2 = pb & 3;
      const float* rp = red[rrg * 2 + bbg][ri][bi2];
      float s = 0.f;
      #pragma unroll
      for (int q = 0; q < 32; ++q) s += rp[(q + tid) & 31];  // bank-rotated
      gates[prow][pb] = s + xpv;
    }
    __syncthreads();

    // ---- nonlinearity + state update (32 threads: (u,b), all in wave 0)
    if (tid < 32) {
      int u = tid >> 3, b = tid & 7;
      float gi = gates[0 * 4 + u][b], gf = gates[1 * 4 + u][b];
      float gg = gates[2 * 4 + u][b], go = gates[3 * 4 + u][b];
      float si = 1.f / (1.f + expf(-gi));
      float sf = 1.f / (1.f + expf(-gf));
      float so = 1.f / (1.f + expf(-go));
      float c = sf * cL[tid] + si * tanhf(gg);
      float h = so * tanhf(c);
      cL[tid] = c;
      // write-through to coherence point (MALL)
      __hip_atomic_store(&hs[(size_t)t * (BN * HN) + b * HN + u0 + u], h,
                         __ATOMIC_RELAXED, __HIP_MEMORY_SCOPE_AGENT);
      if (t == SN - 1) {
        hn[b * HN + u0 + u] = h;
        cn[b * HN + u0 + u] = c;
      }
    }
    // ---- publish: data at MALL (same-wave vmcnt), then tag
    if (t != SN - 1 && tid == 0) {
      asm volatile("s_waitcnt vmcnt(0)" ::: "memory");
      __hip_atomic_store(&tags[(size_t)t * 256 + wg], (unsigned)(t + 1),
                         __ATOMIC_RELAXED, __HIP_MEMORY_SCOPE_AGENT);
    }
    // no end-of-step barrier: hL not rewritten until after next poll-sync
  }
}

// ---------------------------------------------------------------------------
// fp32 -> (bf16 hi, bf16 lo) split
// ---------------------------------------------------------------------------
__global__ __launch_bounds__(256) void k_split(const float* __restrict__ src,
    __bf16* __restrict__ hi, __bf16* __restrict__ lo) {
  int i = (blockIdx.x * 256 + threadIdx.x) * 4;
  f32x4 v = *(const f32x4*)&src[i];
  #pragma unroll
  for (int j = 0; j < 4; ++j) {
    __bf16 h = (__bf16)v[j];
    hi[i + j] = h;
    lo[i + j] = (__bf16)(v[j] - (float)h);
  }
}

// ---------------------------------------------------------------------------
// C[M=2048][N] = A[2048][1024] * Bsrc[N][1024]^T + bias1(+bias2), via
// 3-term bf16 split MFMA. 128x128 tile, BK=32, 4 waves.
// permute=1: output row m=t*8+b is written to row b*256+t (logits layout).
// ---------------------------------------------------------------------------
__global__ __launch_bounds__(256) void k_gemm(const __bf16* __restrict__ Ahi,
    const __bf16* __restrict__ Alo, const float* __restrict__ Bsrc,
    const float* __restrict__ bias1, const float* __restrict__ bias2,
    float* __restrict__ C, int Mt, int N, int permute) {
  __shared__ __bf16 sAh[128][32], sAl[128][32], sBh[128][32], sBl[128][32];
  int bid = blockIdx.x;
  int tn = bid / Mt, tm = bid % Mt;           // m-fastest: B-strip L2 reuse
  int tid = threadIdx.x, lane = tid & 63, wid = tid >> 6;
  int wr = wid >> 1, wc = wid & 1;
  f32x4 acc[4][4] = {};
  const size_t K = 1024;

  for (int kk = 0; kk < 1024; kk += 32) {
    __syncthreads();
    #pragma unroll
    for (int it = 0; it < 2; ++it) {
      int c = it * 256 + tid;                  // 512 chunks of bf16x8
      int r = c >> 2, k8 = (c & 3) * 8;
      size_t ga = (size_t)(tm * 128 + r) * K + kk + k8;
      *(bf16x8*)&sAh[r][k8] = *(const bf16x8*)&Ahi[ga];
      *(bf16x8*)&sAl[r][k8] = *(const bf16x8*)&Alo[ga];
      size_t gb = (size_t)(tn * 128 + r) * K + kk + k8;
      f32x4 x0 = *(const f32x4*)&Bsrc[gb];
      f32x4 x1 = *(const f32x4*)&Bsrc[gb + 4];
      bf16x8 bh, bl;
      #pragma unroll
      for (int j = 0; j < 4; ++j) {
        __bf16 h0 = (__bf16)x0[j]; bh[j]     = h0; bl[j]     = (__bf16)(x0[j] - (float)h0);
        __bf16 h1 = (__bf16)x1[j]; bh[4 + j] = h1; bl[4 + j] = (__bf16)(x1[j] - (float)h1);
      }
      *(bf16x8*)&sBh[r][k8] = bh;
      *(bf16x8*)&sBl[r][k8] = bl;
    }
    __syncthreads();

    int kq = (lane >> 4) * 8;
    bf16x8 ah[4], al[4], bh[4], bl[4];
    #pragma unroll
    for (int i = 0; i < 4; ++i) {
      int ra = wr * 64 + i * 16 + (lane & 15);
      ah[i] = *(const bf16x8*)&sAh[ra][kq];
      al[i] = *(const bf16x8*)&sAl[ra][kq];
      int rb = wc * 64 + i * 16 + (lane & 15);
      bh[i] = *(const bf16x8*)&sBh[rb][kq];
      bl[i] = *(const bf16x8*)&sBl[rb][kq];
    }
    #pragma unroll
    for (int i = 0; i < 4; ++i)
      #pragma unroll
      for (int j = 0; j < 4; ++j) {
        acc[i][j] = __builtin_amdgcn_mfma_f32_16x16x32_bf16(ah[i], bh[j], acc[i][j], 0, 0, 0);
        acc[i][j] = __builtin_amdgcn_mfma_f32_16x16x32_bf16(ah[i], bl[j], acc[i][j], 0, 0, 0);
        acc[i][j] = __builtin_amdgcn_mfma_f32_16x16x32_bf16(al[i], bh[j], acc[i][j], 0, 0, 0);
      }
  }

  // epilogue: C/D layout col=lane&15, row=(lane>>4)*4+reg (m89-verified)
  #pragma unroll
  for (int j = 0; j < 4; ++j) {
    int gcol = tn * 128 + wc * 64 + j * 16 + (lane & 15);
    float bv = bias1[gcol] + (bias2 ? bias2[gcol] : 0.f);
    #pragma unroll
    for (int i = 0; i < 4; ++i) {
      #pragma unroll
      for (int r = 0; r < 4; ++r) {
        int row = tm * 128 + wr * 64 + i * 16 + ((lane >> 4) << 2) + r;
        int orow = permute ? ((row & 7) * 256 + (row >> 3)) : row;
        C[(size_t)orow * N + gcol] = acc[i][j][r] + bv;
      }
    }
  }
}

// ---------------------------------------------------------------------------
extern "C" void kernel_launch(void* const* d_in, const int* in_sizes, int n_in,
                              void* d_out, int out_size, void* d_ws, size_t ws_size,
                              hipStream_t stream) {
  (void)in_sizes; (void)n_in; (void)out_size; (void)ws_size;
  const int*   x     = (const int*)  d_in[0];
  const float* h0    = (const float*)d_in[1];
  const float* c0    = (const float*)d_in[2];
  const float* w_ih0 = (const float*)d_in[3];
  const float* w_hh0 = (const float*)d_in[4];
  const float* b_ih0 = (const float*)d_in[5];
  const float* b_hh0 = (const float*)d_in[6];
  const float* w_ih1 = (const float*)d_in[7];
  const float* w_hh1 = (const float*)d_in[8];
  const float* b_ih1 = (const float*)d_in[9];
  const float* b_hh1 = (const float*)d_in[10];
  const float* fc_w  = (const float*)d_in[11];
  const float* fc_b  = (const float*)d_in[12];
  float* out = (float*)d_out;
  float* ws  = (float*)d_ws;

  // ws layout (floats)
  float* xp   = ws;                        // [S][B][4H] = 8,388,608 (xp1 only)
  float* h1s  = ws + 8388608;              // [S][B][H]  = 2,097,152
  float* h2s  = ws + 10485760;             // 2,097,152
  __bf16* Ahi = (__bf16*)(ws + 12582912);  // 2048*1024 bf16 = 1,048,576 floats
  __bf16* Alo = (__bf16*)(ws + 13631488);  // 1,048,576 floats
  unsigned* tags = (unsigned*)(ws + 14680064); // [256][256] uints = 256KB

  const size_t LOG = (size_t)2048 * VN;    // 65,536,000
  float* hn = out + LOG;                   // [2][8][1024]
  float* cn = out + LOG + 16384;           // [2][8][1024]

  // ---- layer 0 (persistent, fused gather, dataflow sync) ----
  hipMemsetAsync(tags, 0, 65536 * sizeof(unsigned), stream);
  k_lstm<<<256, 256, 0, stream>>>(nullptr, w_ih0, x, b_ih0, b_hh0,
                                  w_hh0, h0, c0, h1s, hn, cn, tags);

  k_split<<<2048, 256, 0, stream>>>(h1s, Ahi, Alo);
  // xp1 = h1s @ w_ih1^T + (b_ih1 + b_hh1)   (M=2048, N=4096)
  k_gemm<<<16 * 32, 256, 0, stream>>>(Ahi, Alo, w_ih1, b_ih1, b_hh1, xp,
                                      16, H4N, 0);

  // ---- layer 1 ----
  hipMemsetAsync(tags, 0, 65536 * sizeof(unsigned), stream);
  k_lstm<<<256, 256, 0, stream>>>(xp, nullptr, nullptr, nullptr, nullptr,
                                  w_hh1, h0 + BN * HN, c0 + BN * HN,
                                  h2s, hn + BN * HN, cn + BN * HN, tags);

  k_split<<<2048, 256, 0, stream>>>(h2s, Ahi, Alo);
  // logits = h2s @ fc_w^T + fc_b  (M=2048, N=32000), row-permuted to b*S+t
  k_gemm<<<16 * 250, 256, 0, stream>>>(Ahi, Alo, fc_w, fc_b, nullptr, out,
                                       16, VN, 1);
}

// Round 9
// 5010.580 us; speedup vs baseline: 1.1277x; 1.0188x over previous
//
#include <hip/hip_runtime.h>
#include <cmath>

typedef float  f32x4  __attribute__((ext_vector_type(4)));
typedef float  f32x2  __attribute__((ext_vector_type(2)));
typedef __bf16 bf16x8 __attribute__((ext_vector_type(8)));

static constexpr int HN  = 1024;     // hidden
static constexpr int VN  = 32000;    // vocab
static constexpr int BN  = 8;        // batch
static constexpr int SN  = 256;      // seq
static constexpr int H4N = 4096;     // 4*H

// ---------------------------------------------------------------------------
// xp0[t][b][r] = w_ih0[r][x[b][t]] + b_ih0[r] + b_hh0[r]   (R5-proven)
// ---------------------------------------------------------------------------
__global__ __launch_bounds__(256) void k_gather(const int* __restrict__ x,
    const float* __restrict__ w_ih0, const float* __restrict__ b_ih0,
    const float* __restrict__ b_hh0, float* __restrict__ xp) {
  int bid = blockIdx.x;
  int t = bid >> 3, b = bid & 7;
  int tok = x[b * SN + t];
  const float* col = w_ih0 + tok;           // column tok, stride VN
  float* dst = xp + (size_t)bid * H4N;
  for (int r = threadIdx.x; r < H4N; r += 256)
    dst[r] = col[(size_t)r * VN] + b_ih0[r] + b_hh0[r];
}

// ---------------------------------------------------------------------------
// Fused 2-layer pipelined persistent LSTM. 256 blocks x 256 thr, 1 block/CU
// (160KiB LDS exactly). Block wg owns units [wg*4,wg*4+4) of BOTH layers.
//
// Super-step s (0..256):
//   mm1: gates1 = w_hh0 @ h1[s-1]  + xp0[s]          (layer0 step s, s<256)
//   mm2: acc2  += w_ih1 @ h1[s-1]                    (xp1 on the fly, s>0)
//   mm3: acc2  += w_hh1 @ h2[s-2]  (+bias)           (layer1 step s-1, s>0)
//   ONE grid sync publishes h1[s] and h2[s-1] together -> 257 syncs total.
//
// Exchange protocol = R5 (best measured): sc1 write-through h stores, same-
// wave vmcnt(0) + relaxed agent RMW on 64 counters x 4 blocks; consumers
// poll relaxed (64 lanes) then read h via sc1 (MALL) u64 loads. No
// invalidates ever -> weights/xp0 stay warm in L2.
//
// LDS: wL0 64KB + wL1 64KB + hL 32KB = 160KiB. hL is phase-multiplexed:
// stage h1 -> mm1/mm2 read -> stage h2 -> mm3 read -> red1/red2 scratch
// (aliased) -> gate values parked at strip[0]. c-state lives in registers.
// w_ih1 slice (64KB/block) streams from L2 (2MB distinct per XCD, resident).
// ---------------------------------------------------------------------------
__global__ __launch_bounds__(256, 1) void k_lstm2(
    const float* __restrict__ xp0,   // [S][B][4H]
    const float* __restrict__ w_hh0, // [4H][H]
    const float* __restrict__ w_ih1, // [4H][H]
    const float* __restrict__ w_hh1, // [4H][H]
    const float* __restrict__ bi1,   // b_ih1
    const float* __restrict__ bh1,   // b_hh1
    const float* __restrict__ h0,    // [2][B][H]
    const float* __restrict__ c0,    // [2][B][H]
    float* __restrict__ h1s,         // [S][B][H] exchange+output
    float* __restrict__ h2s,         // [S][B][H] exchange+output
    float* __restrict__ hn, float* __restrict__ cn,   // [2][B][H]
    unsigned* __restrict__ bar) {    // 64 counters, stride 32 uints
  __shared__ float wL0[16][1024];         // 64KB w_hh0 slice, swizzled
  __shared__ float wL1[16][1024];         // 64KB w_hh1 slice, swizzled
  __shared__ float hL[8192];              // 32KB staging / red1+red2 scratch

  const int tid = threadIdx.x;
  const int wg  = blockIdx.x;
  const int u0  = wg * 4;

  // ---- load both w_hh slices into LDS once (swizzled)
  for (int it = 0; it < 16; ++it) {
    int g = it >> 2, u = it & 3;
    int k4 = tid;
    int k4s = k4 ^ ((k4 >> 3) & 7);
    *(f32x4*)&wL0[it][k4s * 4] =
        *(const f32x4*)&w_hh0[((size_t)g * HN + u0 + u) * HN + k4 * 4];
    *(f32x4*)&wL1[it][k4s * 4] =
        *(const f32x4*)&w_hh1[((size_t)g * HN + u0 + u) * HN + k4 * 4];
  }
  // ---- c-state in registers (tid<32: layer0; tid 32..63: layer1)
  float c1 = 0.f, c2 = 0.f;
  if (tid < 32) c1 = c0[(tid & 7) * HN + u0 + (tid >> 3)];
  else if (tid < 64) {
    int l = tid - 32;
    c2 = c0[BN * HN + (l & 7) * HN + u0 + (l >> 3)];
  }

  const int ks = tid & 31, rg = (tid >> 5) & 3, bg = tid >> 7;
  const int ksx = ks & 7;
  const int hb = tid & 7, hk = tid >> 3;

  // reducer mapping: tid<128 -> gates1(+xp0), tid>=128 -> gates2(+bias1)
  const int prow = (tid & 127) >> 3, pb = tid & 7;
  const int pg = prow >> 2, pu = prow & 3;
  const int grow = pg * HN + u0 + pu;      // global gate row
  float bsum1 = 0.f;
  if (tid >= 128) bsum1 = bi1[grow] + bh1[grow];
  // w_ih1 stream base: thread covers rows {rg*4+ri}, floats [ks*32, ks*32+32)
  const float* wih1_t = w_ih1 + ((size_t)rg * HN + u0) * HN + ks * 32;
  __syncthreads();

  for (int s = 0; s <= SN; ++s) {
    // ---- xp0 prefetch for layer0 step s
    float xpv = 0.f;
    if (s < SN && tid < 128)
      xpv = xp0[(size_t)s * (BN * H4N) + (size_t)pb * H4N + grow];

    // ---- grid sync: all blocks finished super-step s-1
    if (s > 0) {
      if (tid < 64) {
        unsigned tgt = 4u * (unsigned)s;
        while (__hip_atomic_load(&bar[tid * 32], __ATOMIC_RELAXED,
                                 __HIP_MEMORY_SCOPE_AGENT) < tgt)
          __builtin_amdgcn_s_sleep(1);
      }
      __syncthreads();
    }

    // ---- load h1[s-1] (rv1) and h2[s-2] (rv2) via sc1/MALL u64 loads
    unsigned long long rv1[16], rv2[16];
    if (s == 0) {
      const unsigned long long* p =
          (const unsigned long long*)h0 + (size_t)hb * 512 + hk;
      #pragma unroll
      for (int j = 0; j < 16; ++j) rv1[j] = p[j * 32];
    } else {
      const unsigned long long* p =
          (const unsigned long long*)(h1s + (size_t)(s - 1) * (BN * HN))
          + (size_t)hb * 512 + hk;
      #pragma unroll
      for (int j = 0; j < 16; ++j)
        rv1[j] = __hip_atomic_load((unsigned long long*)(p + j * 32),
                                   __ATOMIC_RELAXED, __HIP_MEMORY_SCOPE_AGENT);
      if (s == 1) {
        const unsigned long long* q =
            (const unsigned long long*)(h0 + BN * HN) + (size_t)hb * 512 + hk;
        #pragma unroll
        for (int j = 0; j < 16; ++j) rv2[j] = q[j * 32];
      } else {
        const unsigned long long* q =
            (const unsigned long long*)(h2s + (size_t)(s - 2) * (BN * HN))
            + (size_t)hb * 512 + hk;
        #pragma unroll
        for (int j = 0; j < 16; ++j)
          rv2[j] = __hip_atomic_load((unsigned long long*)(q + j * 32),
                                     __ATOMIC_RELAXED, __HIP_MEMORY_SCOPE_AGENT);
      }
    }

    // ---- phase A: stage h1[s-1] -> hL (swizzled)
    #pragma unroll
    for (int j = 0; j < 16; ++j) {
      int k64 = hk + j * 32, k4 = k64 >> 1, half = k64 & 1;
      int idx = ((k4 << 3) | hb) ^ ((k4 >> 3) & 7);
      *(f32x2*)&hL[idx * 4 + half * 2] = __builtin_bit_cast(f32x2, rv1[j]);
    }
    __syncthreads();

    float acc1[4][4] = {}, acc2[4][4] = {};
    // ---- mm1 (w_hh0, LDS) + mm2 (w_ih1, L2-streamed), both consume h1[s-1]
    #pragma unroll
    for (int j = 0; j < 8; ++j) {
      int k4 = ks * 8 + j;
      int k4s = k4 ^ ksx;
      f32x4 hv[4];
      #pragma unroll
      for (int b2 = 0; b2 < 4; ++b2)
        hv[b2] = *(const f32x4*)&hL[(((k4 << 3) | (bg * 4 + b2)) ^ ksx) * 4];
      if (s < SN) {
        #pragma unroll
        for (int ri = 0; ri < 4; ++ri) {
          f32x4 wv = *(const f32x4*)&wL0[rg * 4 + ri][k4s * 4];
          #pragma unroll
          for (int b2 = 0; b2 < 4; ++b2)
            acc1[ri][b2] += wv[0]*hv[b2][0] + wv[1]*hv[b2][1]
                          + wv[2]*hv[b2][2] + wv[3]*hv[b2][3];
        }
      }
      if (s > 0) {
        #pragma unroll
        for (int ri = 0; ri < 4; ++ri) {
          f32x4 wv = *(const f32x4*)&wih1_t[(size_t)ri * HN + j * 4];
          #pragma unroll
          for (int b2 = 0; b2 < 4; ++b2)
            acc2[ri][b2] += wv[0]*hv[b2][0] + wv[1]*hv[b2][1]
                          + wv[2]*hv[b2][2] + wv[3]*hv[b2][3];
        }
      }
    }

    // ---- phase B: stage h2[s-2] -> hL, mm3 (w_hh1, LDS)
    if (s > 0) {
      __syncthreads();                     // mm1/mm2 done reading hL
      #pragma unroll
      for (int j = 0; j < 16; ++j) {
        int k64 = hk + j * 32, k4 = k64 >> 1, half = k64 & 1;
        int idx = ((k4 << 3) | hb) ^ ((k4 >> 3) & 7);
        *(f32x2*)&hL[idx * 4 + half * 2] = __builtin_bit_cast(f32x2, rv2[j]);
      }
      __syncthreads();
      #pragma unroll
      for (int j = 0; j < 8; ++j) {
        int k4 = ks * 8 + j;
        int k4s = k4 ^ ksx;
        f32x4 hv[4];
        #pragma unroll
        for (int b2 = 0; b2 < 4; ++b2)
          hv[b2] = *(const f32x4*)&hL[(((k4 << 3) | (bg * 4 + b2)) ^ ksx) * 4];
        #pragma unroll
        for (int ri = 0; ri < 4; ++ri) {
          f32x4 wv = *(const f32x4*)&wL1[rg * 4 + ri][k4s * 4];
          #pragma unroll
          for (int b2 = 0; b2 < 4; ++b2)
            acc2[ri][b2] += wv[0]*hv[b2][0] + wv[1]*hv[b2][1]
                          + wv[2]*hv[b2][2] + wv[3]*hv[b2][3];
        }
      }
    }
    __syncthreads();                       // hL free -> becomes red scratch

    // ---- write partials: red1 = hL[0..4096), red2 = hL[4096..8192)
    #pragma unroll
    for (int ri = 0; ri < 4; ++ri)
      #pragma unroll
      for (int b2 = 0; b2 < 4; ++b2) {
        int fo = ((((rg * 2 + bg) * 4 + ri) * 4 + b2) << 5) + ks;
        hL[fo]        = acc1[ri][b2];
        hL[4096 + fo] = acc2[ri][b2];
      }
    __syncthreads();

    // ---- reduce over ks; park gate value at strip[0]
    {
      int fo = ((((prow >> 2) * 2 + (pb >> 2)) * 4 + (prow & 3)) * 4
                + (pb & 3)) << 5;
      float* R = (tid < 128) ? hL : (hL + 4096);
      float sv = 0.f;
      #pragma unroll
      for (int q = 0; q < 32; ++q) sv += R[fo + ((q + tid) & 31)];
      sv += (tid < 128) ? xpv : bsum1;
      R[fo] = sv;
    }
    __syncthreads();

    // ---- nonlinearity layer0 (tid<32): h1[s]
    if (s < SN && tid < 32) {
      int u = tid >> 3, b = tid & 7;
      float gv[4];
      #pragma unroll
      for (int g = 0; g < 4; ++g)
        gv[g] = hL[(((g * 2 + (b >> 2)) * 4 + u) * 4 + (b & 3)) << 5];
      float si = 1.f / (1.f + expf(-gv[0]));
      float sf = 1.f / (1.f + expf(-gv[1]));
      float so = 1.f / (1.f + expf(-gv[3]));
      c1 = sf * c1 + si * tanhf(gv[2]);
      float h = so * tanhf(c1);
      __hip_atomic_store(&h1s[(size_t)s * (BN * HN) + b * HN + u0 + u], h,
                         __ATOMIC_RELAXED, __HIP_MEMORY_SCOPE_AGENT);
      if (s == SN - 1) {
        hn[b * HN + u0 + u] = h;
        cn[b * HN + u0 + u] = c1;
      }
    }
    // ---- nonlinearity layer1 (tid 32..63): h2[s-1]
    if (s > 0 && tid >= 32 && tid < 64) {
      int l = tid - 32, u = l >> 3, b = l & 7;
      float gv[4];
      #pragma unroll
      for (int g = 0; g < 4; ++g)
        gv[g] = hL[4096 + ((((g * 2 + (b >> 2)) * 4 + u) * 4 + (b & 3)) << 5)];
      float si = 1.f / (1.f + expf(-gv[0]));
      float sf = 1.f / (1.f + expf(-gv[1]));
      float so = 1.f / (1.f + expf(-gv[3]));
      c2 = sf * c2 + si * tanhf(gv[2]);
      float h = so * tanhf(c2);
      __hip_atomic_store(&h2s[(size_t)(s - 1) * (BN * HN) + b * HN + u0 + u],
                         h, __ATOMIC_RELAXED, __HIP_MEMORY_SCOPE_AGENT);
      if (s == SN) {
        hn[BN * HN + b * HN + u0 + u] = h;
        cn[BN * HN + b * HN + u0 + u] = c2;
      }
    }

    // ---- arrive: all h stores came from wave 0; tid0 vmcnt(0) orders them
    if (s < SN && tid == 0) {
      asm volatile("s_waitcnt vmcnt(0)" ::: "memory");
      __hip_atomic_fetch_add(&bar[(wg >> 2) * 32], 1u,
                             __ATOMIC_RELAXED, __HIP_MEMORY_SCOPE_AGENT);
    }
    // next iteration's post-poll __syncthreads orders hL reuse
  }
}

// ---------------------------------------------------------------------------
// fp32 -> (bf16 hi, bf16 lo) split
// ---------------------------------------------------------------------------
__global__ __launch_bounds__(256) void k_split(const float* __restrict__ src,
    __bf16* __restrict__ hi, __bf16* __restrict__ lo) {
  int i = (blockIdx.x * 256 + threadIdx.x) * 4;
  f32x4 v = *(const f32x4*)&src[i];
  #pragma unroll
  for (int j = 0; j < 4; ++j) {
    __bf16 h = (__bf16)v[j];
    hi[i + j] = h;
    lo[i + j] = (__bf16)(v[j] - (float)h);
  }
}

// ---------------------------------------------------------------------------
// C[M=2048][N] = A[2048][1024] * Bsrc[N][1024]^T + bias, via 3-term bf16
// split MFMA. 128x128 tile, BK=32, 4 waves. permute=1: row t*8+b -> b*256+t.
// ---------------------------------------------------------------------------
__global__ __launch_bounds__(256) void k_gemm(const __bf16* __restrict__ Ahi,
    const __bf16* __restrict__ Alo, const float* __restrict__ Bsrc,
    const float* __restrict__ bias1, const float* __restrict__ bias2,
    float* __restrict__ C, int Mt, int N, int permute) {
  __shared__ __bf16 sAh[128][32], sAl[128][32], sBh[128][32], sBl[128][32];
  int bid = blockIdx.x;
  int tn = bid / Mt, tm = bid % Mt;
  int tid = threadIdx.x, lane = tid & 63, wid = tid >> 6;
  int wr = wid >> 1, wc = wid & 1;
  f32x4 acc[4][4] = {};
  const size_t K = 1024;

  for (int kk = 0; kk < 1024; kk += 32) {
    __syncthreads();
    #pragma unroll
    for (int it = 0; it < 2; ++it) {
      int c = it * 256 + tid;
      int r = c >> 2, k8 = (c & 3) * 8;
      size_t ga = (size_t)(tm * 128 + r) * K + kk + k8;
      *(bf16x8*)&sAh[r][k8] = *(const bf16x8*)&Ahi[ga];
      *(bf16x8*)&sAl[r][k8] = *(const bf16x8*)&Alo[ga];
      size_t gb = (size_t)(tn * 128 + r) * K + kk + k8;
      f32x4 x0 = *(const f32x4*)&Bsrc[gb];
      f32x4 x1 = *(const f32x4*)&Bsrc[gb + 4];
      bf16x8 bh, bl;
      #pragma unroll
      for (int j = 0; j < 4; ++j) {
        __bf16 h0 = (__bf16)x0[j]; bh[j]     = h0; bl[j]     = (__bf16)(x0[j] - (float)h0);
        __bf16 h1 = (__bf16)x1[j]; bh[4 + j] = h1; bl[4 + j] = (__bf16)(x1[j] - (float)h1);
      }
      *(bf16x8*)&sBh[r][k8] = bh;
      *(bf16x8*)&sBl[r][k8] = bl;
    }
    __syncthreads();

    int kq = (lane >> 4) * 8;
    bf16x8 ah[4], al[4], bh[4], bl[4];
    #pragma unroll
    for (int i = 0; i < 4; ++i) {
      int ra = wr * 64 + i * 16 + (lane & 15);
      ah[i] = *(const bf16x8*)&sAh[ra][kq];
      al[i] = *(const bf16x8*)&sAl[ra][kq];
      int rb = wc * 64 + i * 16 + (lane & 15);
      bh[i] = *(const bf16x8*)&sBh[rb][kq];
      bl[i] = *(const bf16x8*)&sBl[rb][kq];
    }
    #pragma unroll
    for (int i = 0; i < 4; ++i)
      #pragma unroll
      for (int j = 0; j < 4; ++j) {
        acc[i][j] = __builtin_amdgcn_mfma_f32_16x16x32_bf16(ah[i], bh[j], acc[i][j], 0, 0, 0);
        acc[i][j] = __builtin_amdgcn_mfma_f32_16x16x32_bf16(ah[i], bl[j], acc[i][j], 0, 0, 0);
        acc[i][j] = __builtin_amdgcn_mfma_f32_16x16x32_bf16(al[i], bh[j], acc[i][j], 0, 0, 0);
      }
  }

  #pragma unroll
  for (int j = 0; j < 4; ++j) {
    int gcol = tn * 128 + wc * 64 + j * 16 + (lane & 15);
    float bv = bias1[gcol] + (bias2 ? bias2[gcol] : 0.f);
    #pragma unroll
    for (int i = 0; i < 4; ++i) {
      #pragma unroll
      for (int r = 0; r < 4; ++r) {
        int row = tm * 128 + wr * 64 + i * 16 + ((lane >> 4) << 2) + r;
        int orow = permute ? ((row & 7) * 256 + (row >> 3)) : row;
        C[(size_t)orow * N + gcol] = acc[i][j][r] + bv;
      }
    }
  }
}

// ---------------------------------------------------------------------------
extern "C" void kernel_launch(void* const* d_in, const int* in_sizes, int n_in,
                              void* d_out, int out_size, void* d_ws, size_t ws_size,
                              hipStream_t stream) {
  (void)in_sizes; (void)n_in; (void)out_size; (void)ws_size;
  const int*   x     = (const int*)  d_in[0];
  const float* h0    = (const float*)d_in[1];
  const float* c0    = (const float*)d_in[2];
  const float* w_ih0 = (const float*)d_in[3];
  const float* w_hh0 = (const float*)d_in[4];
  const float* b_ih0 = (const float*)d_in[5];
  const float* b_hh0 = (const float*)d_in[6];
  const float* w_ih1 = (const float*)d_in[7];
  const float* w_hh1 = (const float*)d_in[8];
  const float* b_ih1 = (const float*)d_in[9];
  const float* b_hh1 = (const float*)d_in[10];
  const float* fc_w  = (const float*)d_in[11];
  const float* fc_b  = (const float*)d_in[12];
  float* out = (float*)d_out;
  float* ws  = (float*)d_ws;

  // ws layout (floats)
  float* xp0  = ws;                        // [S][B][4H] = 8,388,608
  float* h1s  = ws + 8388608;              // [S][B][H]  = 2,097,152
  float* h2s  = ws + 10485760;             // 2,097,152
  __bf16* Ahi = (__bf16*)(ws + 12582912);  // 2048*1024 bf16
  __bf16* Alo = (__bf16*)(ws + 13631488);
  unsigned* bar = (unsigned*)(ws + 14680064); // 2048 uints (64 x 32)

  const size_t LOG = (size_t)2048 * VN;    // 65,536,000
  float* hn = out + LOG;                   // [2][8][1024]
  float* cn = out + LOG + 16384;           // [2][8][1024]

  hipMemsetAsync(bar, 0, 2048 * sizeof(unsigned), stream);

  k_gather<<<SN * BN, 256, 0, stream>>>(x, w_ih0, b_ih0, b_hh0, xp0);

  // ---- fused 2-layer pipelined LSTM (one persistent launch, 257 syncs)
  k_lstm2<<<256, 256, 0, stream>>>(xp0, w_hh0, w_ih1, w_hh1, b_ih1, b_hh1,
                                   h0, c0, h1s, h2s, hn, cn, bar);

  k_split<<<2048, 256, 0, stream>>>(h2s, Ahi, Alo);
  // logits = h2s @ fc_w^T + fc_b  (M=2048, N=32000), row-permuted to b*S+t
  k_gemm<<<16 * 250, 256, 0, stream>>>(Ahi, Alo, fc_w, fc_b, nullptr, out,
                                       16, VN, 1);
}